// Round 7
// baseline (311.988 us; speedup 1.0000x reference)
//
#include <hip/hip_runtime.h>

#define PI_F 3.14159265358979323846f

// ws layout (bytes):
//   0        : tab  — float ct[512] | st[512] | cp[1024] | sp[1024]
//   12288    : itab — int lo0[512] lo12[512] hi0[512] hi12[512] |
//              rlo[24] @1600 | rhi[24] @1632   (row intervals per plane,band)
//   20480    : losssum float[3]
//   24576    : maxz — u32 maxraw[3*32] then maxdiff[3]
//   32768    : packed hist u8: 3 planes × 32 hists × 262144 bins = 24 MB
//   25198592 : triples u32: 32 images × 524288 points = 64 MB (all 3 planes)
#define ITAB_OFF_B   12288
#define LOSS_OFF_B   20480
#define MAXZ_OFF_B   24576
#define HIST_OFF_B   32768
#define BINS_OFF_B   25198592

// Correctly-rounded a/20000 via Markstein refinement (bit-exact RN).
__device__ inline float div20000(float a) {
    const float r = 1.0f / 20000.0f;
    float q0 = a * r;
    float e = fmaf(-20000.0f, q0, a);
    return fmaf(e, r, q0);
}

__device__ inline int bin1(float v) {
    float f = rintf(div20000(v + 10000.0f) * 512.0f);
    return (int)fminf(fmaxf(f, 0.0f), 511.0f);
}

__global__ void build_tables(float* tab, int* itab, float* losssum,
                             unsigned* maxz) {
    int t = threadIdx.x;
    if (t < 512) {
        float fi = (float)t;
        float theta = -PI_F * (fi / 511.0f - 0.5f);
        float ct = cosf(theta), st = sinf(theta);
        tab[t]       = ct;
        tab[512 + t] = st;
        // Exact per-row y-bin ranges, using the SAME bin1 arithmetic.
        float a0 = 10000.0f * ct;
        int lo0 = max(bin1(-a0) - 1, 0);
        int hi0 = min(bin1(a0) + 1, 511);
        float a1 = -10000.0f * st;
        int lo12, hi12;
        if (st > 0.0f) { lo12 = max(bin1(a1) - 1, 0); hi12 = 256; }
        else           { lo12 = 256; hi12 = min(bin1(a1) + 1, 511); }
        itab[t]        = lo0;
        itab[512 + t]  = lo12;
        itab[1024 + t] = hi0;
        itab[1536 + t] = hi12;
    }
    if (t < 1024) {
        float fj = (float)t;
        float phi = PI_F * ((2.0f * fj) / 1023.0f - 1.0f);
        tab[1024 + t] = cosf(phi);
        tab[2048 + t] = sinf(phi);
    }
    if (t < 3) losssum[t] = 0.0f;
    if (t < 128) maxz[t] = 0u;
    __syncthreads();
    // Visited-row sets per (plane,band) are contiguous intervals (ct unimodal,
    // st monotone in i) — compute [rlo, rhi) from the same itab overlap test.
    if (t < 24) {
        int plane = t >> 3, band = t & 7;
        int off = plane ? 512 : 0;
        int blo = band << 6, bhi = blo + 63;
        int rlo = 512, rhi = 0;
        for (int i = 0; i < 512; ++i) {
            int lo = itab[off + i], hi = itab[1024 + off + i];
            if (blo <= hi && bhi >= lo) { if (i < rlo) rlo = i; rhi = i + 1; }
        }
        itab[1600 + t] = rlo;
        itab[1632 + t] = rhi;
    }
}

// Pass 1: one WG = one (h, row i). One packed triple (iC<<18)|(iB<<9)|iA per
// point serves all 3 planes: p0=(x=iA,y=iB), p1=(x=iA,y=iC), p2=(x=iB,y=iC).
__global__ __launch_bounds__(256) void bin_kernel(
    const float* __restrict__ pred, const float* __restrict__ gt,
    unsigned* __restrict__ bins, const float* __restrict__ tab) {
    const int tid = threadIdx.x, wg = blockIdx.x;
    const int i = wg & 511, h = wg >> 9;
    const float* img = ((h >> 4) ? gt : pred) + ((h & 15) << 19);
    const float4 d4 = *(const float4*)(img + (i << 10) + (tid << 2));
    const float ct = tab[i], st = tab[512 + i];
    const float4 cp4 = *(const float4*)(tab + 1024 + (tid << 2));
    const float4 sp4 = *(const float4*)(tab + 2048 + (tid << 2));
    uint4 o;
    #pragma unroll
    for (int k = 0; k < 4; ++k) {
        float d = (&d4.x)[k];
        float aA = (&cp4.x)[k] * ct;            // identical op order to r3/r5
        float aB = (&sp4.x)[k] * ct;
        float A = (d * aA) * 1000.0f;
        float B = (d * aB) * 1000.0f;
        float C = (d * (-st)) * 1000.0f;
        int iA = bin1(A), iB = bin1(B), iC = bin1(C);
        (&o.x)[k] = ((unsigned)iC << 18) | ((unsigned)iB << 9) | (unsigned)iA;
    }
    *(uint4*)(bins + ((unsigned)h << 19) + (i << 10) + (tid << 2)) = o;
}

// Pass 2: WG = (plane, h, 64-row band); 1024 threads = 16 waves, 2 blocks/CU
// => 32 waves/CU (r6 was 16: the latency-bound fix). Dense contiguous row
// interval; tid>>9 = row parity (2 rows/iteration), uint2 loads.
// blockIdx bits: [0:2]=xcd==h&7 (L2 pin), [3:4]=h>>3, [5:9]=X (LPT order).
__global__ __launch_bounds__(1024, 8) void scan_kernel(
    const unsigned* __restrict__ bins, unsigned* __restrict__ hp,
    unsigned* __restrict__ maxraw, const int* __restrict__ itab) {
    __shared__ unsigned lh[16384];              // 64 rows × 512 bins, u16×2
    __shared__ unsigned s4[16];
    const int tid = threadIdx.x, wg = blockIdx.x;
    const int xcd = wg & 7, hhi = (wg >> 3) & 3;
    const int X = wg >> 5;                      // 0..23
    const int pair = X / 6, idx6 = X % 6;
    const int plane = idx6 >> 1;
    const int band = (idx6 & 1) ? (4 + pair) : (3 - pair);
    const int h = (hhi << 3) | xcd;

    #pragma unroll
    for (int k = 0; k < 4; ++k)
        *(uint4*)&lh[(k << 12) + (tid << 2)] = make_uint4(0, 0, 0, 0);
    __syncthreads();

    // per-plane extraction constants (wave-uniform, in SGPRs)
    int s1, m1, m2, bsh;
    if (plane == 0)      { s1 = 0; m1 = 0x7FFF; m2 = 0;   bsh = 15; }
    else if (plane == 1) { s1 = 9; m1 = 0x7E00; m2 = 511; bsh = 24; }
    else                 { s1 = 9; m1 = 0x7FFF; m2 = 0;   bsh = 24; }
    const unsigned bandu = (unsigned)band;
    const unsigned* src = bins + ((unsigned)h << 19);
    const int rlo = itab[1600 + plane * 8 + band];
    const int rhi = itab[1632 + plane * 8 + band];

    auto process = [&](uint2 v) {
        #pragma unroll
        for (int k = 0; k < 2; ++k) {
            unsigned b = (&v.x)[k];
            if (((b >> bsh) & 7u) == bandu) {
                unsigned id = ((b >> s1) & m1) | (b & m2);
                atomicAdd(&lh[id >> 1], 1u << ((id & 1u) << 4));
            }
        }
    };

    const int t2 = (tid & 511) << 1;
    int r = rlo + (tid >> 9);                   // wave-uniform parity
    bool have = (r < rhi);
    uint2 cur = make_uint2(0u, 0u);
    if (have) cur = *(const uint2*)&src[(r << 10) + t2];
    while (have) {
        int rn = r + 2;
        bool hn = (rn < rhi);
        uint2 nxt = make_uint2(0u, 0u);
        if (hn) nxt = *(const uint2*)&src[(rn << 10) + t2];
        process(cur);
        cur = nxt; r = rn; have = hn;
    }
    __syncthreads();

    // pack to u8 (sat 255; downstream clamps at 100) + raw band max
    unsigned m = 0;
    unsigned* gout = hp + ((plane * 32 + h) << 16) + (band << 13);
    #pragma unroll
    for (int k = 0; k < 8; ++k) {
        int w = (k << 10) + tid;
        unsigned v0 = lh[2 * w], v1 = lh[2 * w + 1];
        unsigned c0 = v0 & 65535u, c1 = v0 >> 16;
        unsigned c2 = v1 & 65535u, c3 = v1 >> 16;
        m = max(max(m, max(c0, c1)), max(c2, c3));
        gout[w] = min(c0, 255u) | (min(c1, 255u) << 8) |
                  (min(c2, 255u) << 16) | (min(c3, 255u) << 24);
    }
    #pragma unroll
    for (int o = 32; o; o >>= 1) m = max(m, (unsigned)__shfl_down((int)m, o));
    if ((tid & 63) == 0) s4[tid >> 6] = m;
    __syncthreads();
    if (tid == 0) {
        #pragma unroll
        for (int k = 1; k < 16; ++k) m = max(m, s4[k]);
        atomicMax(&maxraw[plane * 32 + h], m);
    }
}

__device__ inline float blockMaxF(float v) {
    #pragma unroll
    for (int o = 32; o; o >>= 1) v = fmaxf(v, __shfl_down(v, o));
    __shared__ float s[4];
    if ((threadIdx.x & 63) == 0) s[threadIdx.x >> 6] = v;
    __syncthreads();
    if (threadIdx.x == 0) v = fmaxf(fmaxf(s[0], s[1]), fmaxf(s[2], s[3]));
    return v;
}

__device__ inline float blockSumF(float v) {
    #pragma unroll
    for (int o = 32; o; o >>= 1) v += __shfl_down(v, o);
    __shared__ float s[4];
    if ((threadIdx.x & 63) == 0) s[threadIdx.x >> 6] = v;
    __syncthreads();
    if (threadIdx.x == 0) v = (s[0] + s[1]) + (s[2] + s[3]);
    return v;
}

// 768 blocks = 3 planes × 16 b × 16 chunks; uint4 loads, 16 bins/word-quad.
__global__ void maxdiff_kernel(const unsigned* __restrict__ hp,
                               const unsigned* __restrict__ maxraw,
                               unsigned* __restrict__ maxdiff) {
    int blk = blockIdx.x;
    int b = blk & 15, chunk = (blk >> 4) & 15, plane = blk >> 8;
    const unsigned* P = hp + ((plane * 32 + b) << 16) + (chunk << 12);
    const unsigned* G = P + (16 << 16);
    float nP = fminf((float)maxraw[plane * 32 + b], 100.0f);
    float nG = fminf((float)maxraw[plane * 32 + 16 + b], 100.0f);
    float m = 0.0f;
    #pragma unroll
    for (int k = 0; k < 4; ++k) {
        uint4 wp = *(const uint4*)&P[(k << 10) + (threadIdx.x << 2)];
        uint4 wg = *(const uint4*)&G[(k << 10) + (threadIdx.x << 2)];
        #pragma unroll
        for (int w = 0; w < 4; ++w) {
            unsigned up = (&wp.x)[w], ug = (&wg.x)[w];
            #pragma unroll
            for (int s = 0; s < 32; s += 8) {
                float pn = fminf((float)((up >> s) & 255u), 100.0f) / nP;
                float gn = fminf((float)((ug >> s) & 255u), 100.0f) / nG;
                m = fmaxf(m, fabsf(pn - gn));
            }
        }
    }
    m = blockMaxF(m);
    if (threadIdx.x == 0) atomicMax(&maxdiff[plane], __float_as_uint(m));
}

__global__ void loss_kernel(const unsigned* __restrict__ hp,
                            const unsigned* __restrict__ maxraw,
                            const unsigned* __restrict__ maxdiff,
                            float* __restrict__ losssum) {
    int blk = blockIdx.x;
    int b = blk & 15, chunk = (blk >> 4) & 15, plane = blk >> 8;
    const unsigned* P = hp + ((plane * 32 + b) << 16) + (chunk << 12);
    const unsigned* G = P + (16 << 16);
    float c = 0.2f * __uint_as_float(maxdiff[plane]);
    float nP = fminf((float)maxraw[plane * 32 + b], 100.0f);
    float nG = fminf((float)maxraw[plane * 32 + 16 + b], 100.0f);
    float acc = 0.0f;
    #pragma unroll
    for (int k = 0; k < 4; ++k) {
        uint4 wp = *(const uint4*)&P[(k << 10) + (threadIdx.x << 2)];
        uint4 wg = *(const uint4*)&G[(k << 10) + (threadIdx.x << 2)];
        #pragma unroll
        for (int w = 0; w < 4; ++w) {
            unsigned up = (&wp.x)[w], ug = (&wg.x)[w];
            #pragma unroll
            for (int s = 0; s < 32; s += 8) {
                float pn = fminf((float)((up >> s) & 255u), 100.0f) / nP;
                float gn = fminf((float)((ug >> s) & 255u), 100.0f) / nG;
                float d = fabsf(pn - gn);
                acc += (d <= c) ? d : (d * d + c * c) / (2.0f * c);
            }
        }
    }
    acc = blockSumF(acc);
    if (threadIdx.x == 0) atomicAdd(&losssum[plane], acc);
}

__global__ void finalize_kernel(const float* __restrict__ losssum,
                                float* __restrict__ out) {
    out[0] = losssum[0] / 4194304.0f + losssum[1] / 4194304.0f +
             losssum[2] / 4194304.0f;
}

extern "C" void kernel_launch(void* const* d_in, const int* in_sizes, int n_in,
                              void* d_out, int out_size, void* d_ws, size_t ws_size,
                              hipStream_t stream) {
    const float* pred = (const float*)d_in[0];
    const float* gt   = (const float*)d_in[1];
    float* out        = (float*)d_out;
    char* ws          = (char*)d_ws;

    float*    tab     = (float*)ws;
    int*      itab    = (int*)(ws + ITAB_OFF_B);
    float*    losssum = (float*)(ws + LOSS_OFF_B);
    unsigned* maxz    = (unsigned*)(ws + MAXZ_OFF_B);
    unsigned* maxraw  = maxz;
    unsigned* maxdiff = maxz + 96;
    unsigned* hp      = (unsigned*)(ws + HIST_OFF_B);
    unsigned* bins    = (unsigned*)(ws + BINS_OFF_B);

    build_tables<<<1, 1024, 0, stream>>>(tab, itab, losssum, maxz);
    bin_kernel<<<16384, 256, 0, stream>>>(pred, gt, bins, tab);
    scan_kernel<<<768, 1024, 0, stream>>>(bins, hp, maxraw, itab);
    maxdiff_kernel<<<768, 256, 0, stream>>>(hp, maxraw, maxdiff);
    loss_kernel<<<768, 256, 0, stream>>>(hp, maxraw, maxdiff, losssum);
    finalize_kernel<<<1, 1, 0, stream>>>(losssum, out);
}

// Round 8
// 285.806 us; speedup vs baseline: 1.0916x; 1.0916x over previous
//
#include <hip/hip_runtime.h>

#define PI_F 3.14159265358979323846f

// ws layout (bytes):
//   0        : tab  — float ct[512] | st[512] | cp[1024] | sp[1024]
//   12288    : itab — rlo[24] @1600 | rhi[24] @1632 (row intervals per plane,band)
//   20480    : losssum float[3]
//   24576    : maxz — u32 maxraw[3*32] then maxdiff[3]
//   32768    : packed hist u8: 3 planes × 32 hists × 262144 bins = 24 MB
//   25198592 : triples u32: 32 images × 524288 points = 64 MB (all 3 planes)
#define ITAB_OFF_B   12288
#define LOSS_OFF_B   20480
#define MAXZ_OFF_B   24576
#define HIST_OFF_B   32768
#define BINS_OFF_B   25198592

// Correctly-rounded a/20000 via Markstein refinement (bit-exact RN).
__device__ inline float div20000(float a) {
    const float r = 1.0f / 20000.0f;
    float q0 = a * r;
    float e = fmaf(-20000.0f, q0, a);
    return fmaf(e, r, q0);
}

__device__ inline int bin1(float v) {
    float f = rintf(div20000(v + 10000.0f) * 512.0f);
    return (int)fminf(fmaxf(f, 0.0f), 511.0f);
}

// r7 lesson: NO serial global-load loops here — this runs on the critical
// path before bin_kernel. Intervals via LDS atomics from per-thread registers.
__global__ void build_tables(float* tab, int* itab, float* losssum,
                             unsigned* maxz) {
    __shared__ int srlo[16], srhi[16];          // [table0/12][band]
    int t = threadIdx.x;
    if (t < 16) { srlo[t] = 512; srhi[t] = 0; }
    __syncthreads();
    if (t < 512) {
        float fi = (float)t;
        float theta = -PI_F * (fi / 511.0f - 0.5f);
        float ct = cosf(theta), st = sinf(theta);
        tab[t]       = ct;
        tab[512 + t] = st;
        // Exact per-row y-bin ranges, using the SAME bin1 arithmetic.
        float a0 = 10000.0f * ct;
        int lo0 = max(bin1(-a0) - 1, 0);
        int hi0 = min(bin1(a0) + 1, 511);
        float a1 = -10000.0f * st;
        int lo12, hi12;
        if (st > 0.0f) { lo12 = max(bin1(a1) - 1, 0); hi12 = 256; }
        else           { lo12 = 256; hi12 = min(bin1(a1) + 1, 511); }
        #pragma unroll
        for (int band = 0; band < 8; ++band) {
            int blo = band << 6, bhi = blo + 63;
            if (blo <= hi0 && bhi >= lo0) {
                atomicMin(&srlo[band], t); atomicMax(&srhi[band], t + 1);
            }
            if (blo <= hi12 && bhi >= lo12) {
                atomicMin(&srlo[8 + band], t); atomicMax(&srhi[8 + band], t + 1);
            }
        }
    }
    if (t < 1024) {
        float fj = (float)t;
        float phi = PI_F * ((2.0f * fj) / 1023.0f - 1.0f);
        tab[1024 + t] = cosf(phi);
        tab[2048 + t] = sinf(phi);
    }
    if (t < 3) losssum[t] = 0.0f;
    if (t < 128) maxz[t] = 0u;
    __syncthreads();
    if (t < 24) {
        int plane = t >> 3, band = t & 7;
        int c = (plane ? 8 : 0) + band;
        itab[1600 + t] = srlo[c];
        itab[1632 + t] = srhi[c];
    }
}

// Pass 1: one WG = one (h, row i). One packed triple (iC<<18)|(iB<<9)|iA per
// point serves all 3 planes: p0=(x=iA,y=iB), p1=(x=iA,y=iC), p2=(x=iB,y=iC).
__global__ __launch_bounds__(256) void bin_kernel(
    const float* __restrict__ pred, const float* __restrict__ gt,
    unsigned* __restrict__ bins, const float* __restrict__ tab) {
    const int tid = threadIdx.x, wg = blockIdx.x;
    const int i = wg & 511, h = wg >> 9;
    const float* img = ((h >> 4) ? gt : pred) + ((h & 15) << 19);
    const float4 d4 = *(const float4*)(img + (i << 10) + (tid << 2));
    const float ct = tab[i], st = tab[512 + i];
    const float4 cp4 = *(const float4*)(tab + 1024 + (tid << 2));
    const float4 sp4 = *(const float4*)(tab + 2048 + (tid << 2));
    uint4 o;
    #pragma unroll
    for (int k = 0; k < 4; ++k) {
        float d = (&d4.x)[k];
        float aA = (&cp4.x)[k] * ct;            // identical op order to r3/r5
        float aB = (&sp4.x)[k] * ct;
        float A = (d * aA) * 1000.0f;
        float B = (d * aB) * 1000.0f;
        float C = (d * (-st)) * 1000.0f;
        int iA = bin1(A), iB = bin1(B), iC = bin1(C);
        (&o.x)[k] = ((unsigned)iC << 18) | ((unsigned)iB << 9) | (unsigned)iA;
    }
    *(uint4*)(bins + ((unsigned)h << 19) + (i << 10) + (tid << 2)) = o;
}

// Pass 2: WG = (plane, h, 64-row band); 1024 threads = 16 waves, 2 blocks/CU
// => 32 waves/CU. Dense contiguous row interval; tid>>9 = row parity
// (2 rows/iteration), uint2 loads, 1-deep prefetch.
// blockIdx bits: [0:2]=xcd==h&7 (L2 pin), [3:4]=h>>3, [5:9]=X (LPT order).
__global__ __launch_bounds__(1024, 8) void scan_kernel(
    const unsigned* __restrict__ bins, unsigned* __restrict__ hp,
    unsigned* __restrict__ maxraw, const int* __restrict__ itab) {
    __shared__ unsigned lh[16384];              // 64 rows × 512 bins, u16×2
    __shared__ unsigned s4[16];
    const int tid = threadIdx.x, wg = blockIdx.x;
    const int xcd = wg & 7, hhi = (wg >> 3) & 3;
    const int X = wg >> 5;                      // 0..23
    const int pair = X / 6, idx6 = X % 6;
    const int plane = idx6 >> 1;
    const int band = (idx6 & 1) ? (4 + pair) : (3 - pair);
    const int h = (hhi << 3) | xcd;

    #pragma unroll
    for (int k = 0; k < 4; ++k)
        *(uint4*)&lh[(k << 12) + (tid << 2)] = make_uint4(0, 0, 0, 0);
    __syncthreads();

    // per-plane extraction constants (wave-uniform, in SGPRs)
    int s1, m1, m2, bsh;
    if (plane == 0)      { s1 = 0; m1 = 0x7FFF; m2 = 0;   bsh = 15; }
    else if (plane == 1) { s1 = 9; m1 = 0x7E00; m2 = 511; bsh = 24; }
    else                 { s1 = 9; m1 = 0x7FFF; m2 = 0;   bsh = 24; }
    const unsigned bandu = (unsigned)band;
    const unsigned* src = bins + ((unsigned)h << 19);
    const int rlo = itab[1600 + plane * 8 + band];
    const int rhi = itab[1632 + plane * 8 + band];

    auto process = [&](uint2 v) {
        #pragma unroll
        for (int k = 0; k < 2; ++k) {
            unsigned b = (&v.x)[k];
            if (((b >> bsh) & 7u) == bandu) {
                unsigned id = ((b >> s1) & m1) | (b & m2);
                atomicAdd(&lh[id >> 1], 1u << ((id & 1u) << 4));
            }
        }
    };

    const int t2 = (tid & 511) << 1;
    int r = rlo + (tid >> 9);                   // wave-uniform parity
    bool have = (r < rhi);
    uint2 cur = make_uint2(0u, 0u);
    if (have) cur = *(const uint2*)&src[(r << 10) + t2];
    while (have) {
        int rn = r + 2;
        bool hn = (rn < rhi);
        uint2 nxt = make_uint2(0u, 0u);
        if (hn) nxt = *(const uint2*)&src[(rn << 10) + t2];
        process(cur);
        cur = nxt; r = rn; have = hn;
    }
    __syncthreads();

    // pack to u8 (sat 255; downstream clamps at 100) + raw band max
    unsigned m = 0;
    unsigned* gout = hp + ((plane * 32 + h) << 16) + (band << 13);
    #pragma unroll
    for (int k = 0; k < 8; ++k) {
        int w = (k << 10) + tid;
        unsigned v0 = lh[2 * w], v1 = lh[2 * w + 1];
        unsigned c0 = v0 & 65535u, c1 = v0 >> 16;
        unsigned c2 = v1 & 65535u, c3 = v1 >> 16;
        m = max(max(m, max(c0, c1)), max(c2, c3));
        gout[w] = min(c0, 255u) | (min(c1, 255u) << 8) |
                  (min(c2, 255u) << 16) | (min(c3, 255u) << 24);
    }
    #pragma unroll
    for (int o = 32; o; o >>= 1) m = max(m, (unsigned)__shfl_down((int)m, o));
    if ((tid & 63) == 0) s4[tid >> 6] = m;
    __syncthreads();
    if (tid == 0) {
        #pragma unroll
        for (int k = 1; k < 16; ++k) m = max(m, s4[k]);
        atomicMax(&maxraw[plane * 32 + h], m);
    }
}

__device__ inline float blockMaxF(float v) {
    #pragma unroll
    for (int o = 32; o; o >>= 1) v = fmaxf(v, __shfl_down(v, o));
    __shared__ float s[4];
    if ((threadIdx.x & 63) == 0) s[threadIdx.x >> 6] = v;
    __syncthreads();
    if (threadIdx.x == 0) v = fmaxf(fmaxf(s[0], s[1]), fmaxf(s[2], s[3]));
    return v;
}

__device__ inline float blockSumF(float v) {
    #pragma unroll
    for (int o = 32; o; o >>= 1) v += __shfl_down(v, o);
    __shared__ float s[4];
    if ((threadIdx.x & 63) == 0) s[threadIdx.x >> 6] = v;
    __syncthreads();
    if (threadIdx.x == 0) v = (s[0] + s[1]) + (s[2] + s[3]);
    return v;
}

// 768 blocks = 3 planes × 16 b × 16 chunks; uint4 loads, 16 bins/word-quad.
__global__ void maxdiff_kernel(const unsigned* __restrict__ hp,
                               const unsigned* __restrict__ maxraw,
                               unsigned* __restrict__ maxdiff) {
    int blk = blockIdx.x;
    int b = blk & 15, chunk = (blk >> 4) & 15, plane = blk >> 8;
    const unsigned* P = hp + ((plane * 32 + b) << 16) + (chunk << 12);
    const unsigned* G = P + (16 << 16);
    float nP = fminf((float)maxraw[plane * 32 + b], 100.0f);
    float nG = fminf((float)maxraw[plane * 32 + 16 + b], 100.0f);
    float m = 0.0f;
    #pragma unroll
    for (int k = 0; k < 4; ++k) {
        uint4 wp = *(const uint4*)&P[(k << 10) + (threadIdx.x << 2)];
        uint4 wg = *(const uint4*)&G[(k << 10) + (threadIdx.x << 2)];
        #pragma unroll
        for (int w = 0; w < 4; ++w) {
            unsigned up = (&wp.x)[w], ug = (&wg.x)[w];
            #pragma unroll
            for (int s = 0; s < 32; s += 8) {
                float pn = fminf((float)((up >> s) & 255u), 100.0f) / nP;
                float gn = fminf((float)((ug >> s) & 255u), 100.0f) / nG;
                m = fmaxf(m, fabsf(pn - gn));
            }
        }
    }
    m = blockMaxF(m);
    if (threadIdx.x == 0) atomicMax(&maxdiff[plane], __float_as_uint(m));
}

__global__ void loss_kernel(const unsigned* __restrict__ hp,
                            const unsigned* __restrict__ maxraw,
                            const unsigned* __restrict__ maxdiff,
                            float* __restrict__ losssum) {
    int blk = blockIdx.x;
    int b = blk & 15, chunk = (blk >> 4) & 15, plane = blk >> 8;
    const unsigned* P = hp + ((plane * 32 + b) << 16) + (chunk << 12);
    const unsigned* G = P + (16 << 16);
    float c = 0.2f * __uint_as_float(maxdiff[plane]);
    float nP = fminf((float)maxraw[plane * 32 + b], 100.0f);
    float nG = fminf((float)maxraw[plane * 32 + 16 + b], 100.0f);
    float acc = 0.0f;
    #pragma unroll
    for (int k = 0; k < 4; ++k) {
        uint4 wp = *(const uint4*)&P[(k << 10) + (threadIdx.x << 2)];
        uint4 wg = *(const uint4*)&G[(k << 10) + (threadIdx.x << 2)];
        #pragma unroll
        for (int w = 0; w < 4; ++w) {
            unsigned up = (&wp.x)[w], ug = (&wg.x)[w];
            #pragma unroll
            for (int s = 0; s < 32; s += 8) {
                float pn = fminf((float)((up >> s) & 255u), 100.0f) / nP;
                float gn = fminf((float)((ug >> s) & 255u), 100.0f) / nG;
                float d = fabsf(pn - gn);
                acc += (d <= c) ? d : (d * d + c * c) / (2.0f * c);
            }
        }
    }
    acc = blockSumF(acc);
    if (threadIdx.x == 0) atomicAdd(&losssum[plane], acc);
}

__global__ void finalize_kernel(const float* __restrict__ losssum,
                                float* __restrict__ out) {
    out[0] = losssum[0] / 4194304.0f + losssum[1] / 4194304.0f +
             losssum[2] / 4194304.0f;
}

extern "C" void kernel_launch(void* const* d_in, const int* in_sizes, int n_in,
                              void* d_out, int out_size, void* d_ws, size_t ws_size,
                              hipStream_t stream) {
    const float* pred = (const float*)d_in[0];
    const float* gt   = (const float*)d_in[1];
    float* out        = (float*)d_out;
    char* ws          = (char*)d_ws;

    float*    tab     = (float*)ws;
    int*      itab    = (int*)(ws + ITAB_OFF_B);
    float*    losssum = (float*)(ws + LOSS_OFF_B);
    unsigned* maxz    = (unsigned*)(ws + MAXZ_OFF_B);
    unsigned* maxraw  = maxz;
    unsigned* maxdiff = maxz + 96;
    unsigned* hp      = (unsigned*)(ws + HIST_OFF_B);
    unsigned* bins    = (unsigned*)(ws + BINS_OFF_B);

    build_tables<<<1, 1024, 0, stream>>>(tab, itab, losssum, maxz);
    bin_kernel<<<16384, 256, 0, stream>>>(pred, gt, bins, tab);
    scan_kernel<<<768, 1024, 0, stream>>>(bins, hp, maxraw, itab);
    maxdiff_kernel<<<768, 256, 0, stream>>>(hp, maxraw, maxdiff);
    loss_kernel<<<768, 256, 0, stream>>>(hp, maxraw, maxdiff, losssum);
    finalize_kernel<<<1, 1, 0, stream>>>(losssum, out);
}

// Round 9
// 263.908 us; speedup vs baseline: 1.1822x; 1.0830x over previous
//
#include <hip/hip_runtime.h>

#define PI_F 3.14159265358979323846f

// ws layout (bytes):
//   0        : tab  — float ct[512] | st[512] | cp[1024] | sp[1024]
//   12288    : itab — rlo[24] @1600 | rhi[24] @1632 (row intervals per plane,band)
//   24576    : maxz — u32 maxraw[3*32] then maxdiff[3]
//   32768    : packed hist u8: 3 planes × 32 hists × 262144 bins = 24 MB
//   25198592 : triples u32: 32 images × 524288 points = 64 MB (all 3 planes)
#define ITAB_OFF_B   12288
#define MAXZ_OFF_B   24576
#define HIST_OFF_B   32768
#define BINS_OFF_B   25198592

// Correctly-rounded a/20000 via Markstein refinement (bit-exact RN).
__device__ inline float div20000(float a) {
    const float r = 1.0f / 20000.0f;
    float q0 = a * r;
    float e = fmaf(-20000.0f, q0, a);
    return fmaf(e, r, q0);
}

__device__ inline int bin1(float v) {
    float f = rintf(div20000(v + 10000.0f) * 512.0f);
    return (int)fminf(fmaxf(f, 0.0f), 511.0f);
}

// No serial global-load loops here (r7 lesson) — intervals via LDS atomics.
// Also zeroes out[0] (loss kernel accumulates into it; finalize fused away).
__global__ void build_tables(float* tab, int* itab, unsigned* maxz,
                             float* out) {
    __shared__ int srlo[16], srhi[16];          // [table0/12][band]
    int t = threadIdx.x;
    if (t < 16) { srlo[t] = 512; srhi[t] = 0; }
    __syncthreads();
    if (t < 512) {
        float fi = (float)t;
        float theta = -PI_F * (fi / 511.0f - 0.5f);
        float ct = cosf(theta), st = sinf(theta);
        tab[t]       = ct;
        tab[512 + t] = st;
        // Exact per-row y-bin ranges, using the SAME bin1 arithmetic.
        float a0 = 10000.0f * ct;
        int lo0 = max(bin1(-a0) - 1, 0);
        int hi0 = min(bin1(a0) + 1, 511);
        float a1 = -10000.0f * st;
        int lo12, hi12;
        if (st > 0.0f) { lo12 = max(bin1(a1) - 1, 0); hi12 = 256; }
        else           { lo12 = 256; hi12 = min(bin1(a1) + 1, 511); }
        #pragma unroll
        for (int band = 0; band < 8; ++band) {
            int blo = band << 6, bhi = blo + 63;
            if (blo <= hi0 && bhi >= lo0) {
                atomicMin(&srlo[band], t); atomicMax(&srhi[band], t + 1);
            }
            if (blo <= hi12 && bhi >= lo12) {
                atomicMin(&srlo[8 + band], t); atomicMax(&srhi[8 + band], t + 1);
            }
        }
    }
    if (t < 1024) {
        float fj = (float)t;
        float phi = PI_F * ((2.0f * fj) / 1023.0f - 1.0f);
        tab[1024 + t] = cosf(phi);
        tab[2048 + t] = sinf(phi);
    }
    if (t == 0) out[0] = 0.0f;
    if (t < 128) maxz[t] = 0u;
    __syncthreads();
    if (t < 24) {
        int plane = t >> 3, band = t & 7;
        int c = (plane ? 8 : 0) + band;
        itab[1600 + t] = srlo[c];
        itab[1632 + t] = srhi[c];
    }
}

// Pass 1: one WG = one (h, row i), XCD-PINNED: wg&7 == h&7, matching scan's
// reader pinning so image h's bin stream is written from (and partially
// retained in) XCD h&7's L2. One packed triple (iC<<18)|(iB<<9)|iA per point
// serves all 3 planes: p0=(x=iA,y=iB), p1=(x=iA,y=iC), p2=(x=iB,y=iC).
__global__ __launch_bounds__(256) void bin_kernel(
    const float* __restrict__ pred, const float* __restrict__ gt,
    unsigned* __restrict__ bins, const float* __restrict__ tab) {
    const int tid = threadIdx.x, wg = blockIdx.x;
    const int xcd = wg & 7, i = (wg >> 3) & 511, hh = wg >> 12;
    const int h = (hh << 3) | xcd;
    const float* img = ((h >> 4) ? gt : pred) + ((h & 15) << 19);
    const float4 d4 = *(const float4*)(img + (i << 10) + (tid << 2));
    const float ct = tab[i], st = tab[512 + i];
    const float4 cp4 = *(const float4*)(tab + 1024 + (tid << 2));
    const float4 sp4 = *(const float4*)(tab + 2048 + (tid << 2));
    uint4 o;
    #pragma unroll
    for (int k = 0; k < 4; ++k) {
        float d = (&d4.x)[k];
        float aA = (&cp4.x)[k] * ct;            // identical op order to r3/r5
        float aB = (&sp4.x)[k] * ct;
        float A = (d * aA) * 1000.0f;
        float B = (d * aB) * 1000.0f;
        float C = (d * (-st)) * 1000.0f;
        int iA = bin1(A), iB = bin1(B), iC = bin1(C);
        (&o.x)[k] = ((unsigned)iC << 18) | ((unsigned)iB << 9) | (unsigned)iA;
    }
    *(uint4*)(bins + ((unsigned)h << 19) + (i << 10) + (tid << 2)) = o;
}

// Pass 2: WG = (plane, h, 64-row band); 1024 threads, 2 blocks/CU = 32
// waves/CU. uint4 loads: 4 points/thread, 4 rows/block-iteration, 1-deep
// prefetch. blockIdx bits: [0:2]=xcd==h&7 (L2 pin), [3:4]=h>>3, [5:9]=X
// (LPT order: center bands first).
__global__ __launch_bounds__(1024, 8) void scan_kernel(
    const unsigned* __restrict__ bins, unsigned* __restrict__ hp,
    unsigned* __restrict__ maxraw, const int* __restrict__ itab) {
    __shared__ unsigned lh[16384];              // 64 rows × 512 bins, u16×2
    __shared__ unsigned s4[16];
    const int tid = threadIdx.x, wg = blockIdx.x;
    const int xcd = wg & 7, hhi = (wg >> 3) & 3;
    const int X = wg >> 5;                      // 0..23
    const int pair = X / 6, idx6 = X % 6;
    const int plane = idx6 >> 1;
    const int band = (idx6 & 1) ? (4 + pair) : (3 - pair);
    const int h = (hhi << 3) | xcd;

    #pragma unroll
    for (int k = 0; k < 4; ++k)
        *(uint4*)&lh[(k << 12) + (tid << 2)] = make_uint4(0, 0, 0, 0);
    __syncthreads();

    // per-plane extraction constants (wave-uniform, in SGPRs)
    int s1, m1, m2, bsh;
    if (plane == 0)      { s1 = 0; m1 = 0x7FFF; m2 = 0;   bsh = 15; }
    else if (plane == 1) { s1 = 9; m1 = 0x7E00; m2 = 511; bsh = 24; }
    else                 { s1 = 9; m1 = 0x7FFF; m2 = 0;   bsh = 24; }
    const unsigned bandu = (unsigned)band;
    const unsigned* src = bins + ((unsigned)h << 19);
    const int rlo = itab[1600 + plane * 8 + band];
    const int rhi = itab[1632 + plane * 8 + band];

    auto process = [&](uint4 v) {
        #pragma unroll
        for (int k = 0; k < 4; ++k) {
            unsigned b = (&v.x)[k];
            if (((b >> bsh) & 7u) == bandu) {
                unsigned id = ((b >> s1) & m1) | (b & m2);
                atomicAdd(&lh[id >> 1], 1u << ((id & 1u) << 4));
            }
        }
    };

    const int t4 = (tid & 255) << 2;            // column group (4 points)
    const int rof = tid >> 8;                   // 0..3 row offset (wave-unif)
    int r = rlo + rof;
    uint4 cur = make_uint4(0u, 0u, 0u, 0u);
    if (r < rhi) cur = *(const uint4*)&src[(r << 10) + t4];
    for (int rbase = rlo; rbase < rhi; rbase += 4) {
        int rn = rbase + 4 + rof;
        uint4 nxt = make_uint4(0u, 0u, 0u, 0u);
        if (rn < rhi) nxt = *(const uint4*)&src[(rn << 10) + t4];
        if (rbase + rof < rhi) process(cur);
        cur = nxt;
    }
    __syncthreads();

    // pack to u8 (sat 255; downstream clamps at 100) + raw band max
    unsigned m = 0;
    unsigned* gout = hp + ((plane * 32 + h) << 16) + (band << 13);
    #pragma unroll
    for (int k = 0; k < 8; ++k) {
        int w = (k << 10) + tid;
        unsigned v0 = lh[2 * w], v1 = lh[2 * w + 1];
        unsigned c0 = v0 & 65535u, c1 = v0 >> 16;
        unsigned c2 = v1 & 65535u, c3 = v1 >> 16;
        m = max(max(m, max(c0, c1)), max(c2, c3));
        gout[w] = min(c0, 255u) | (min(c1, 255u) << 8) |
                  (min(c2, 255u) << 16) | (min(c3, 255u) << 24);
    }
    #pragma unroll
    for (int o = 32; o; o >>= 1) m = max(m, (unsigned)__shfl_down((int)m, o));
    if ((tid & 63) == 0) s4[tid >> 6] = m;
    __syncthreads();
    if (tid == 0) {
        #pragma unroll
        for (int k = 1; k < 16; ++k) m = max(m, s4[k]);
        atomicMax(&maxraw[plane * 32 + h], m);
    }
}

__device__ inline float blockMaxF(float v) {
    #pragma unroll
    for (int o = 32; o; o >>= 1) v = fmaxf(v, __shfl_down(v, o));
    __shared__ float s[4];
    if ((threadIdx.x & 63) == 0) s[threadIdx.x >> 6] = v;
    __syncthreads();
    if (threadIdx.x == 0) v = fmaxf(fmaxf(s[0], s[1]), fmaxf(s[2], s[3]));
    return v;
}

__device__ inline float blockSumF(float v) {
    #pragma unroll
    for (int o = 32; o; o >>= 1) v += __shfl_down(v, o);
    __shared__ float s[4];
    if ((threadIdx.x & 63) == 0) s[threadIdx.x >> 6] = v;
    __syncthreads();
    if (threadIdx.x == 0) v = (s[0] + s[1]) + (s[2] + s[3]);
    return v;
}

// 768 blocks = 3 planes × 16 b × 16 chunks; uint4 loads, 16 bins/word-quad.
__global__ void maxdiff_kernel(const unsigned* __restrict__ hp,
                               const unsigned* __restrict__ maxraw,
                               unsigned* __restrict__ maxdiff) {
    int blk = blockIdx.x;
    int b = blk & 15, chunk = (blk >> 4) & 15, plane = blk >> 8;
    const unsigned* P = hp + ((plane * 32 + b) << 16) + (chunk << 12);
    const unsigned* G = P + (16 << 16);
    float nP = fminf((float)maxraw[plane * 32 + b], 100.0f);
    float nG = fminf((float)maxraw[plane * 32 + 16 + b], 100.0f);
    float m = 0.0f;
    #pragma unroll
    for (int k = 0; k < 4; ++k) {
        uint4 wp = *(const uint4*)&P[(k << 10) + (threadIdx.x << 2)];
        uint4 wg = *(const uint4*)&G[(k << 10) + (threadIdx.x << 2)];
        #pragma unroll
        for (int w = 0; w < 4; ++w) {
            unsigned up = (&wp.x)[w], ug = (&wg.x)[w];
            #pragma unroll
            for (int s = 0; s < 32; s += 8) {
                float pn = fminf((float)((up >> s) & 255u), 100.0f) / nP;
                float gn = fminf((float)((ug >> s) & 255u), 100.0f) / nG;
                m = fmaxf(m, fabsf(pn - gn));
            }
        }
    }
    m = blockMaxF(m);
    if (threadIdx.x == 0) atomicMax(&maxdiff[plane], __float_as_uint(m));
}

// Accumulates directly into out[0] (pre-zeroed by build_tables):
// blocksum/2^22 is an exact power-of-2 scale, then one atomicAdd per block.
__global__ void loss_kernel(const unsigned* __restrict__ hp,
                            const unsigned* __restrict__ maxraw,
                            const unsigned* __restrict__ maxdiff,
                            float* __restrict__ out) {
    int blk = blockIdx.x;
    int b = blk & 15, chunk = (blk >> 4) & 15, plane = blk >> 8;
    const unsigned* P = hp + ((plane * 32 + b) << 16) + (chunk << 12);
    const unsigned* G = P + (16 << 16);
    float c = 0.2f * __uint_as_float(maxdiff[plane]);
    float nP = fminf((float)maxraw[plane * 32 + b], 100.0f);
    float nG = fminf((float)maxraw[plane * 32 + 16 + b], 100.0f);
    float acc = 0.0f;
    #pragma unroll
    for (int k = 0; k < 4; ++k) {
        uint4 wp = *(const uint4*)&P[(k << 10) + (threadIdx.x << 2)];
        uint4 wg = *(const uint4*)&G[(k << 10) + (threadIdx.x << 2)];
        #pragma unroll
        for (int w = 0; w < 4; ++w) {
            unsigned up = (&wp.x)[w], ug = (&wg.x)[w];
            #pragma unroll
            for (int s = 0; s < 32; s += 8) {
                float pn = fminf((float)((up >> s) & 255u), 100.0f) / nP;
                float gn = fminf((float)((ug >> s) & 255u), 100.0f) / nG;
                float d = fabsf(pn - gn);
                acc += (d <= c) ? d : (d * d + c * c) / (2.0f * c);
            }
        }
    }
    acc = blockSumF(acc);
    if (threadIdx.x == 0) atomicAdd(out, acc / 4194304.0f);
}

extern "C" void kernel_launch(void* const* d_in, const int* in_sizes, int n_in,
                              void* d_out, int out_size, void* d_ws, size_t ws_size,
                              hipStream_t stream) {
    const float* pred = (const float*)d_in[0];
    const float* gt   = (const float*)d_in[1];
    float* out        = (float*)d_out;
    char* ws          = (char*)d_ws;

    float*    tab     = (float*)ws;
    int*      itab    = (int*)(ws + ITAB_OFF_B);
    unsigned* maxz    = (unsigned*)(ws + MAXZ_OFF_B);
    unsigned* maxraw  = maxz;
    unsigned* maxdiff = maxz + 96;
    unsigned* hp      = (unsigned*)(ws + HIST_OFF_B);
    unsigned* bins    = (unsigned*)(ws + BINS_OFF_B);

    build_tables<<<1, 1024, 0, stream>>>(tab, itab, maxz, out);
    bin_kernel<<<16384, 256, 0, stream>>>(pred, gt, bins, tab);
    scan_kernel<<<768, 1024, 0, stream>>>(bins, hp, maxraw, itab);
    maxdiff_kernel<<<768, 256, 0, stream>>>(hp, maxraw, maxdiff);
    loss_kernel<<<768, 256, 0, stream>>>(hp, maxraw, maxdiff, out);
}

// Round 10
// 226.052 us; speedup vs baseline: 1.3802x; 1.1675x over previous
//
#include <hip/hip_runtime.h>

#define PI_F 3.14159265358979323846f

// ws layout (bytes):
//   24576    : maxz — u32 maxraw[3*32] then maxdiff[3] (zeroed by bin block 0)
//   32768    : packed hist u8: 3 planes × 32 hists × 262144 bins = 24 MB
//   25198592 : triples u32: 32 images × 524288 points = 64 MB (all 3 planes)
#define MAXZ_OFF_B   24576
#define HIST_OFF_B   32768
#define BINS_OFF_B   25198592

// Correctly-rounded a/20000 via Markstein refinement (bit-exact RN).
__device__ inline float div20000(float a) {
    const float r = 1.0f / 20000.0f;
    float q0 = a * r;
    float e = fmaf(-20000.0f, q0, a);
    return fmaf(e, r, q0);
}

__device__ inline int bin1(float v) {
    float f = rintf(div20000(v + 10000.0f) * 512.0f);
    return (int)fminf(fmaxf(f, 0.0f), 511.0f);
}

// Pass 1 (tables fused away): 4096 blocks = (xcd[0:2], i4[3:9], hh[10:11]),
// 4 rows/block, XCD-pinned (wg&7 == h&7). Trig computed in-kernel with the
// EXACT same expressions the old build_tables used -> bit-identical bins.
// Block 0 zeroes maxz + out (ordered before scan/loss by kernel boundary).
__global__ __launch_bounds__(256) void bin_kernel(
    const float* __restrict__ pred, const float* __restrict__ gt,
    unsigned* __restrict__ bins, unsigned* __restrict__ maxz,
    float* __restrict__ out) {
    __shared__ float sct[4], sst[4];
    const int tid = threadIdx.x, wg = blockIdx.x;
    const int xcd = wg & 7, i4 = (wg >> 3) & 127, hh = wg >> 10;
    const int h = (hh << 3) | xcd;
    if (wg == 0) {
        if (tid < 128) maxz[tid] = 0u;
        if (tid == 128) out[0] = 0.0f;
    }
    if (tid < 4) {
        float fi = (float)(i4 * 4 + tid);
        float theta = -PI_F * (fi / 511.0f - 0.5f);
        sct[tid] = cosf(theta);
        sst[tid] = sinf(theta);
    }
    float cp[4], sp[4];
    #pragma unroll
    for (int k = 0; k < 4; ++k) {
        float fj = (float)(tid * 4 + k);
        float phi = PI_F * ((2.0f * fj) / 1023.0f - 1.0f);
        cp[k] = cosf(phi);
        sp[k] = sinf(phi);
    }
    __syncthreads();
    const float* img = ((h >> 4) ? gt : pred) + ((h & 15) << 19);
    #pragma unroll
    for (int r = 0; r < 4; ++r) {
        const int i = i4 * 4 + r;
        const float4 d4 = *(const float4*)(img + (i << 10) + (tid << 2));
        const float ct = sct[r], st = sst[r];
        uint4 o;
        #pragma unroll
        for (int k = 0; k < 4; ++k) {
            float d = (&d4.x)[k];
            float aA = cp[k] * ct;              // identical op order to r3/r5
            float aB = sp[k] * ct;
            float A = (d * aA) * 1000.0f;
            float B = (d * aB) * 1000.0f;
            float C = (d * (-st)) * 1000.0f;
            int iA = bin1(A), iB = bin1(B), iC = bin1(C);
            (&o.x)[k] = ((unsigned)iC << 18) | ((unsigned)iB << 9) | (unsigned)iA;
        }
        *(uint4*)(bins + ((unsigned)h << 19) + (i << 10) + (tid << 2)) = o;
    }
}

// Pass 2: WG = (plane, h, 64-row band); 1024 threads, 2 blocks/CU = 32
// waves/CU; uint4 loads, 1-deep prefetch. Row interval computed ANALYTICALLY
// (conservative superset of the r8/r9 exact interval, +4-row slack — extra
// rows hold zero in-band points, so counts are bit-identical).
// blockIdx bits: [0:2]=xcd==h&7 (L2 pin), [3:4]=h>>3, [5:9]=X (LPT order).
__global__ __launch_bounds__(1024, 8) void scan_kernel(
    const unsigned* __restrict__ bins, unsigned* __restrict__ hp,
    unsigned* __restrict__ maxraw) {
    __shared__ unsigned lh[16384];              // 64 rows × 512 bins, u16×2
    __shared__ unsigned s4[16];
    const int tid = threadIdx.x, wg = blockIdx.x;
    const int xcd = wg & 7, hhi = (wg >> 3) & 3;
    const int X = wg >> 5;                      // 0..23
    const int pair = X / 6, idx6 = X % 6;
    const int plane = idx6 >> 1;
    const int band = (idx6 & 1) ? (4 + pair) : (3 - pair);
    const int h = (hhi << 3) | xcd;

    #pragma unroll
    for (int k = 0; k < 4; ++k)
        *(uint4*)&lh[(k << 12) + (tid << 2)] = make_uint4(0, 0, 0, 0);
    __syncthreads();

    // analytic conservative row interval (wave-uniform)
    int rlo, rhi;
    if (plane == 0) {
        float g = fmaxf(193.0f - 64.0f * band, 64.0f * band - 256.0f);
        float cmin = (g - 4.0f) * (1.0f / 256.0f);
        if (cmin <= 0.0f) { rlo = 0; rhi = 512; }
        else {
            float L = 511.0f * acosf(fminf(cmin, 1.0f)) / PI_F;
            rlo = max(0, (int)floorf(255.5f - L) - 3);
            rhi = min(512, (int)ceilf(255.5f + L) + 4);
        }
    } else if (band == 3) { rlo = 0; rhi = 260; }   // st>0 rows only (+slack)
    else if (band == 4) { rlo = 0; rhi = 512; }     // always touches bin 256
    else if (band < 3) {
        float smin = (189.0f - 64.0f * band) * (1.0f / 256.0f);
        rlo = 0;
        rhi = min(512, (int)ceilf(511.0f * (0.5f - asinf(smin) / PI_F)) + 4);
    } else {
        float smin = (64.0f * band - 260.0f) * (1.0f / 256.0f);
        rhi = 512;
        rlo = max(0, (int)floorf(511.0f * (0.5f + asinf(smin) / PI_F)) - 4);
    }

    // per-plane extraction constants (wave-uniform, in SGPRs)
    int s1, m1, m2, bsh;
    if (plane == 0)      { s1 = 0; m1 = 0x7FFF; m2 = 0;   bsh = 15; }
    else if (plane == 1) { s1 = 9; m1 = 0x7E00; m2 = 511; bsh = 24; }
    else                 { s1 = 9; m1 = 0x7FFF; m2 = 0;   bsh = 24; }
    const unsigned bandu = (unsigned)band;
    const unsigned* src = bins + ((unsigned)h << 19);

    auto process = [&](uint4 v) {
        #pragma unroll
        for (int k = 0; k < 4; ++k) {
            unsigned b = (&v.x)[k];
            if (((b >> bsh) & 7u) == bandu) {
                unsigned id = ((b >> s1) & m1) | (b & m2);
                atomicAdd(&lh[id >> 1], 1u << ((id & 1u) << 4));
            }
        }
    };

    const int t4 = (tid & 255) << 2;            // column group (4 points)
    const int rof = tid >> 8;                   // 0..3 row offset (wave-unif)
    int r = rlo + rof;
    uint4 cur = make_uint4(0u, 0u, 0u, 0u);
    if (r < rhi) cur = *(const uint4*)&src[(r << 10) + t4];
    for (int rbase = rlo; rbase < rhi; rbase += 4) {
        int rn = rbase + 4 + rof;
        uint4 nxt = make_uint4(0u, 0u, 0u, 0u);
        if (rn < rhi) nxt = *(const uint4*)&src[(rn << 10) + t4];
        if (rbase + rof < rhi) process(cur);
        cur = nxt;
    }
    __syncthreads();

    // pack to u8 (sat 255; downstream clamps at 100) + raw band max
    unsigned m = 0;
    unsigned* gout = hp + ((plane * 32 + h) << 16) + (band << 13);
    #pragma unroll
    for (int k = 0; k < 8; ++k) {
        int w = (k << 10) + tid;
        unsigned v0 = lh[2 * w], v1 = lh[2 * w + 1];
        unsigned c0 = v0 & 65535u, c1 = v0 >> 16;
        unsigned c2 = v1 & 65535u, c3 = v1 >> 16;
        m = max(max(m, max(c0, c1)), max(c2, c3));
        gout[w] = min(c0, 255u) | (min(c1, 255u) << 8) |
                  (min(c2, 255u) << 16) | (min(c3, 255u) << 24);
    }
    #pragma unroll
    for (int o = 32; o; o >>= 1) m = max(m, (unsigned)__shfl_down((int)m, o));
    if ((tid & 63) == 0) s4[tid >> 6] = m;
    __syncthreads();
    if (tid == 0) {
        #pragma unroll
        for (int k = 1; k < 16; ++k) m = max(m, s4[k]);
        atomicMax(&maxraw[plane * 32 + h], m);
    }
}

__device__ inline float blockMaxF(float v) {
    #pragma unroll
    for (int o = 32; o; o >>= 1) v = fmaxf(v, __shfl_down(v, o));
    __shared__ float s[4];
    if ((threadIdx.x & 63) == 0) s[threadIdx.x >> 6] = v;
    __syncthreads();
    if (threadIdx.x == 0) v = fmaxf(fmaxf(s[0], s[1]), fmaxf(s[2], s[3]));
    return v;
}

__device__ inline float blockSumF(float v) {
    #pragma unroll
    for (int o = 32; o; o >>= 1) v += __shfl_down(v, o);
    __shared__ float s[4];
    if ((threadIdx.x & 63) == 0) s[threadIdx.x >> 6] = v;
    __syncthreads();
    if (threadIdx.x == 0) v = (s[0] + s[1]) + (s[2] + s[3]);
    return v;
}

// 768 blocks = 3 planes × 16 b × 16 chunks; uint4 loads, 16 bins/word-quad.
__global__ void maxdiff_kernel(const unsigned* __restrict__ hp,
                               const unsigned* __restrict__ maxraw,
                               unsigned* __restrict__ maxdiff) {
    int blk = blockIdx.x;
    int b = blk & 15, chunk = (blk >> 4) & 15, plane = blk >> 8;
    const unsigned* P = hp + ((plane * 32 + b) << 16) + (chunk << 12);
    const unsigned* G = P + (16 << 16);
    float nP = fminf((float)maxraw[plane * 32 + b], 100.0f);
    float nG = fminf((float)maxraw[plane * 32 + 16 + b], 100.0f);
    float m = 0.0f;
    #pragma unroll
    for (int k = 0; k < 4; ++k) {
        uint4 wp = *(const uint4*)&P[(k << 10) + (threadIdx.x << 2)];
        uint4 wg = *(const uint4*)&G[(k << 10) + (threadIdx.x << 2)];
        #pragma unroll
        for (int w = 0; w < 4; ++w) {
            unsigned up = (&wp.x)[w], ug = (&wg.x)[w];
            #pragma unroll
            for (int s = 0; s < 32; s += 8) {
                float pn = fminf((float)((up >> s) & 255u), 100.0f) / nP;
                float gn = fminf((float)((ug >> s) & 255u), 100.0f) / nG;
                m = fmaxf(m, fabsf(pn - gn));
            }
        }
    }
    m = blockMaxF(m);
    if (threadIdx.x == 0) atomicMax(&maxdiff[plane], __float_as_uint(m));
}

// Accumulates directly into out[0] (pre-zeroed by bin block 0):
// blocksum/2^22 is an exact power-of-2 scale, then one atomicAdd per block.
__global__ void loss_kernel(const unsigned* __restrict__ hp,
                            const unsigned* __restrict__ maxraw,
                            const unsigned* __restrict__ maxdiff,
                            float* __restrict__ out) {
    int blk = blockIdx.x;
    int b = blk & 15, chunk = (blk >> 4) & 15, plane = blk >> 8;
    const unsigned* P = hp + ((plane * 32 + b) << 16) + (chunk << 12);
    const unsigned* G = P + (16 << 16);
    float c = 0.2f * __uint_as_float(maxdiff[plane]);
    float nP = fminf((float)maxraw[plane * 32 + b], 100.0f);
    float nG = fminf((float)maxraw[plane * 32 + 16 + b], 100.0f);
    float acc = 0.0f;
    #pragma unroll
    for (int k = 0; k < 4; ++k) {
        uint4 wp = *(const uint4*)&P[(k << 10) + (threadIdx.x << 2)];
        uint4 wg = *(const uint4*)&G[(k << 10) + (threadIdx.x << 2)];
        #pragma unroll
        for (int w = 0; w < 4; ++w) {
            unsigned up = (&wp.x)[w], ug = (&wg.x)[w];
            #pragma unroll
            for (int s = 0; s < 32; s += 8) {
                float pn = fminf((float)((up >> s) & 255u), 100.0f) / nP;
                float gn = fminf((float)((ug >> s) & 255u), 100.0f) / nG;
                float d = fabsf(pn - gn);
                acc += (d <= c) ? d : (d * d + c * c) / (2.0f * c);
            }
        }
    }
    acc = blockSumF(acc);
    if (threadIdx.x == 0) atomicAdd(out, acc / 4194304.0f);
}

extern "C" void kernel_launch(void* const* d_in, const int* in_sizes, int n_in,
                              void* d_out, int out_size, void* d_ws, size_t ws_size,
                              hipStream_t stream) {
    const float* pred = (const float*)d_in[0];
    const float* gt   = (const float*)d_in[1];
    float* out        = (float*)d_out;
    char* ws          = (char*)d_ws;

    unsigned* maxz    = (unsigned*)(ws + MAXZ_OFF_B);
    unsigned* maxraw  = maxz;
    unsigned* maxdiff = maxz + 96;
    unsigned* hp      = (unsigned*)(ws + HIST_OFF_B);
    unsigned* bins    = (unsigned*)(ws + BINS_OFF_B);

    bin_kernel<<<4096, 256, 0, stream>>>(pred, gt, bins, maxz, out);
    scan_kernel<<<768, 1024, 0, stream>>>(bins, hp, maxraw);
    maxdiff_kernel<<<768, 256, 0, stream>>>(hp, maxraw, maxdiff);
    loss_kernel<<<768, 256, 0, stream>>>(hp, maxraw, maxdiff, out);
}